// Round 9
// baseline (79.107 us; speedup 1.0000x reference)
//
#include <hip/hip_runtime.h>
#include <math.h>

// HypAgg (Poincare ball, c=1), 3 dispatches.
//   g_ij = att_ij * atanh(sn_ij)/sn_ij / den_ij
//   support_i = beta_i * ( -S_i x_i + beta_i Y_i ),  S=sum g*alpha, Y=sum g x_j
// hyp_prep: bf16 SWIZZLED images of x (row-major XbSw + transposed XbtSw) + row
//   stats. Swizzle: 16B chunk k of row r stored at position k^(r&15) -> a
//   contiguous global_load_lds yields an LDS image whose b128 frag reads are
//   bank-balanced (8 words/bank = minimum for wave64 b128).
// hyp_main: staging is PURE DMA (17x global_load_lds width=16 per thread, no
//   f2bf, no LDS writes) — r2/r5/r8 all ~15us exec because staging was
//   VALU-bound (~900 ops/thread); this removes ~550 of them.
// hyp_exp : sums partials + expmap.
// ws floats: Yp[8*131072] | Sp2[8*1024*64] | st_x2[1024] | st_L[1024] | st_R[1024]
//            | XbSw[131072 shorts] | XbtSw[131072 shorts]

typedef short short4v __attribute__((ext_vector_type(4)));
typedef short short8v __attribute__((ext_vector_type(8)));
typedef float float4v __attribute__((ext_vector_type(4)));

static __device__ __forceinline__ short f2bf(float f) {
    unsigned u = __float_as_uint(f);
    u += 0x7fff + ((u >> 16) & 1);   // RNE; inputs never NaN here
    return (short)(u >> 16);
}
static __device__ __forceinline__ float bf2f(unsigned short s) {
    return __uint_as_float(((unsigned)s) << 16);
}
static __device__ __forceinline__ float rcpf(float x) { return __builtin_amdgcn_rcpf(x); }
static __device__ __forceinline__ float dot4(float4v a, float4v b) {
    return a[0]*b[0] + a[1]*b[1] + a[2]*b[2] + a[3]*b[3];
}
static __device__ __forceinline__ float atanh_over(float pn) {   // atanh(min(pn,1-eps))/pn
    float uu = fminf(pn, 1.f - 1e-7f);
    return 0.5f * __logf((1.f + uu) * rcpf(1.f - uu)) * rcpf(pn);
}
static __device__ __forceinline__ void glds16(const void* g, void* l) {
    __builtin_amdgcn_global_load_lds(
        (const __attribute__((address_space(1))) void*)g,
        (__attribute__((address_space(3))) void*)l, 16, 0, 0);
}

// ---------------- kernel 1: swizzled bf16 images + row stats ----------------
// grid 16: blocks 0..7 -> XbSw chunk c + stats for rows [128c,128c+128);
//          blocks 8..15 -> XbtSw chunk c-8.
__global__ __launch_bounds__(256) void hyp_prep(
    const float* __restrict__ x, const float* __restrict__ w,
    const float* __restrict__ battp,
    unsigned short* __restrict__ XbSw, unsigned short* __restrict__ XbtSw,
    float* __restrict__ st_x2, float* __restrict__ st_L, float* __restrict__ st_R)
{
    __shared__ __align__(16) unsigned short sT[128 * 128];  // swizzled bf16 tile
    __shared__ float sWf[256];
    __shared__ float sPx[256], sPl[256], sPr[256];
    const int t  = threadIdx.x;
    const int bx = blockIdx.x;
    const bool typeA = bx < 8;
    const int c  = typeA ? bx : bx - 8;
    const float4v* x4 = (const float4v*)x;
    const float4v* w4 = (const float4v*)w;

    if (t < 64) *(float4v*)&sWf[t * 4] = w4[t];

    // ---- stage 128x128 fp32 -> swizzled bf16 LDS (and global XbSw for type A) ----
#pragma unroll
    for (int it = 0; it < 16; ++it) {
        int idx  = t + it * 256;           // 0..4095
        int r    = idx >> 5;               // local row 0..127
        int col4 = idx & 31;               // float4 index
        float4v v = x4[(c * 128 + r) * 32 + col4];
        short4v h = { f2bf(v[0]), f2bf(v[1]), f2bf(v[2]), f2bf(v[3]) };
        int pos = (col4 >> 1) ^ (r & 15);
        int off = r * 128 + pos * 8 + (col4 & 1) * 4;   // shorts
        *(short4v*)&sT[off] = h;
        if (typeA) *(short4v*)&XbSw[c * 16384 + off] = h;
    }
    __syncthreads();

    if (typeA) {
        // ---- j-stats from swizzled LDS: t -> (row j = t>>1, half ph = t&1) ----
        int j = t >> 1, ph = t & 1;
        float x2 = 0.f, dl = 0.f, dr = 0.f;
#pragma unroll
        for (int p = 0; p < 8; ++p) {
            int pp = ph * 8 + p;
            short8v v = *(const short8v*)&sT[j * 128 + pp * 8];
            int kbase = (pp ^ (j & 15)) * 8;           // logical element base
#pragma unroll
            for (int e = 0; e < 8; ++e) {
                float f = bf2f((unsigned short)v[e]);
                x2 = fmaf(f, f, x2);
                dl = fmaf(f, sWf[kbase + e], dl);
                dr = fmaf(f, sWf[128 + kbase + e], dr);
            }
        }
        sPx[t] = x2; sPl[t] = dl; sPr[t] = dr;
        __syncthreads();
        if (t < 128) {
            float x2s = sPx[2 * t] + sPx[2 * t + 1];
            float dls = sPl[2 * t] + sPl[2 * t + 1];
            float drs = sPr[2 * t] + sPr[2 * t + 1];
            float pn  = sqrtf(fmaxf(x2s, 1e-15f));
            float f   = atanh_over(pn);
            int row = c * 128 + t;
            st_x2[row] = x2s;
            st_L [row] = dls * f + battp[0];
            st_R [row] = drs * f;
        }
    } else {
        // ---- transposed image: t -> (dim d = t>>1, j-half jh = t&1) ----
        int d = t >> 1, jh = t & 1;
        unsigned short tmp[64];
#pragma unroll
        for (int jj = 0; jj < 64; ++jj) {
            int j = jh * 64 + jj;
            tmp[jj] = sT[j * 128 + (((d >> 3) ^ (j & 15)) * 8) + (d & 7)];
        }
#pragma unroll
        for (int k8 = 0; k8 < 8; ++k8) {
            int ktl = jh * 8 + k8;
            int pt  = ktl ^ (d & 15);
            *(short8v*)&XbtSw[c * 16384 + d * 128 + pt * 8] = *(const short8v*)&tmp[k8 * 8];
        }
    }
}

// ---------------- kernel 2: pairwise MFMA + scalar map (DMA staging) ----------------
__global__ __launch_bounds__(256, 2) void hyp_main(
    const unsigned short* __restrict__ XbSw, const unsigned short* __restrict__ XbtSw,
    const float* __restrict__ adj,
    const float* __restrict__ st_x2, const float* __restrict__ st_L,
    const float* __restrict__ st_R,
    float* __restrict__ Yp, float* __restrict__ Sp2)
{
    __shared__ __align__(16) unsigned short sXI [16 * 128];   // swizzled, pitch 256B
    __shared__ __align__(16) unsigned short sXJ [128 * 128];
    __shared__ __align__(16) unsigned short sXJt[128 * 128];
    __shared__ __align__(16) unsigned short sW  [16 * 128];   // swizzled like rows

    const int t    = threadIdx.x;
    const int lane = t & 63;
    const int wave = t >> 6;
    const int n    = lane & 15;
    const int q    = lane >> 4;
    const int i0   = blockIdx.x * 16;
    const int c    = blockIdx.y;
    const int j0   = c * 128;

    // ---- register prefetch (independent; overlaps DMA) ----
    float x2i4[4], bi4[4], li4[4];
#pragma unroll
    for (int r = 0; r < 4; ++r) {
        int i = i0 + q * 4 + r;
        x2i4[r] = st_x2[i];
        li4[r]  = st_L[i];
    }
    float x2j2[2], rj2[2], adjv[2][4];
#pragma unroll
    for (int jsl = 0; jsl < 2; ++jsl) {
        int j = j0 + (wave * 2 + jsl) * 16 + n;
        x2j2[jsl] = st_x2[j];
        rj2[jsl]  = st_R[j];
#pragma unroll
        for (int r = 0; r < 4; ++r)
            adjv[jsl][r] = adj[(i0 + q * 4 + r) * 1024 + j];
    }
#pragma unroll
    for (int r = 0; r < 4; ++r) bi4[r] = 1.f - x2i4[r];

    // ---- staging: pure DMA (wave-uniform base + lane*16) ----
    {
        const char* gXI  = (const char*)(XbSw + i0 * 128);
        const char* gXJ  = (const char*)(XbSw + c * 16384);
        const char* gXJt = (const char*)(XbtSw + c * 16384);
        int wo = wave * 1024 + lane * 16;
        glds16(gXI + wo, (char*)sXI + wo);
#pragma unroll
        for (int it = 0; it < 8; ++it) {
            glds16(gXJ  + it * 4096 + wo, (char*)sXJ  + it * 4096 + wo);
            glds16(gXJt + it * 4096 + wo, (char*)sXJt + it * 4096 + wo);
        }
    }
    __builtin_amdgcn_s_waitcnt(0);   // drain DMA before barrier (belt & braces)
    __syncthreads();                 // B1

    // ---- A-frags: row n, logical chunk kk*4+q at pos ^ n ----
    short8v afrag[4];
#pragma unroll
    for (int kk = 0; kk < 4; ++kk)
        afrag[kk] = *(const short8v*)&sXI[n * 128 + (((kk * 4 + q) ^ n)) * 8];

    float Sacc[4];

    // ---- phase A: G = X_I * X_J^T + scalar map -> sW, Sacc ----
#pragma unroll
    for (int jsl = 0; jsl < 2; ++jsl) {
        int js = wave * 2 + jsl;
        int jrow = js * 16 + n;        // jrow & 15 == n
        float4v acc = (float4v){0.f, 0.f, 0.f, 0.f};
#pragma unroll
        for (int kk = 0; kk < 4; ++kk) {
            short8v b = *(const short8v*)&sXJ[jrow * 128 + (((kk * 4 + q) ^ n)) * 8];
            acc = __builtin_amdgcn_mfma_f32_16x16x32_bf16(afrag[kk], b, acc, 0, 0, 0);
        }
        float x2j = x2j2[jsl];
        float rj  = rj2[jsl];
#pragma unroll
        for (int r = 0; r < 4; ++r) {
            float G     = acc[r];
            int   i     = q * 4 + r;
            float alpha = 1.f - 2.f * G + x2j;
            float den   = fmaxf(fmaf(x2i4[r], x2j, 1.f - 2.f * G), 1e-15f);
            float rdn   = rcpf(den);
            float bb    = bi4[r];
            float nn2   = alpha * alpha * x2i4[r] + bb * bb * x2j - 2.f * alpha * bb * G;
            float sn    = sqrtf(fmaxf(nn2 * rdn * rdn, 1e-15f));
            float tt    = atanh_over(sn);
            float z     = li4[r] + rj;
            float sig   = rcpf(1.f + __expf(-z));
            float g     = sig * adjv[jsl][r] * tt * rdn;
            if (jsl == 0) Sacc[r] = g * alpha; else Sacc[r] = fmaf(g, alpha, Sacc[r]);
            // col = js*16+n -> chunk js*2+(n>>3), elem n&7; pos = chunk ^ i
            sW[i * 128 + ((js * 2 + (n >> 3)) ^ i) * 8 + (n & 7)] = (unsigned short)f2bf(g);
        }
    }
    __syncthreads();   // B2: sW ready

    // ---- phase B: Y = W(16x128) * X_J(128x128) via sXJt ----
    float4v accB[2];
    accB[0] = (float4v){0.f, 0.f, 0.f, 0.f};
    accB[1] = (float4v){0.f, 0.f, 0.f, 0.f};
#pragma unroll
    for (int nsl = 0; nsl < 2; ++nsl) {
        int ns = wave * 2 + nsl;
        int drow = ns * 16 + n;        // drow & 15 == n
#pragma unroll
        for (int kk = 0; kk < 4; ++kk) {
            short8v a = *(const short8v*)&sW  [n * 128    + (((kk * 4 + q) ^ n)) * 8];
            short8v b = *(const short8v*)&sXJt[drow * 128 + (((kk * 4 + q) ^ n)) * 8];
            accB[nsl] = __builtin_amdgcn_mfma_f32_16x16x32_bf16(a, b, accB[nsl], 0, 0, 0);
        }
    }

    // ---- stores: Y partials + raw S partials (no reduction, no barrier) ----
    float* Yc = Yp + c * 131072;
#pragma unroll
    for (int nsl = 0; nsl < 2; ++nsl) {
        int ns = wave * 2 + nsl;
#pragma unroll
        for (int r = 0; r < 4; ++r)
            Yc[(i0 + q * 4 + r) * 128 + ns * 16 + n] = accB[nsl][r];
    }
#pragma unroll
    for (int r = 0; r < 4; ++r)
        Sp2[((c * 1024 + i0 + q * 4 + r) * 4 + wave) * 16 + n] = Sacc[r];
}

// ---------------- kernel 3: sum partials + expmap ----------------
// 128 blocks x 256 threads: 8 rows/block, 32 lanes/row, 4 dims/lane.
__global__ __launch_bounds__(256) void hyp_exp(
    const float* __restrict__ x, const float* __restrict__ Yp,
    const float* __restrict__ Sp2, const float* __restrict__ st_x2,
    float* __restrict__ out)
{
    const int t   = threadIdx.x;
    const int row = blockIdx.x * 8 + (t >> 5);
    const int l32 = t & 31;
    float4v y = (float4v){0.f, 0.f, 0.f, 0.f};
    float S = 0.f;
#pragma unroll
    for (int c = 0; c < 8; ++c) {
        y += *(const float4v*)&Yp[c * 131072 + row * 128 + l32 * 4];
        S += Sp2[(c * 1024 + row) * 64 + l32];
        S += Sp2[(c * 1024 + row) * 64 + 32 + l32];
    }
#pragma unroll
    for (int m = 1; m < 32; m <<= 1) S += __shfl_xor(S, m, 32);

    float4v xa = ((const float4v*)x)[row * 32 + l32];
    float x2 = st_x2[row];
    float bE = fmaxf(1.f - x2, 1e-15f);
    float u[4], un2p = 0.f, xup = 0.f;
#pragma unroll
    for (int e = 0; e < 4; ++e) {
        u[e] = bE * (bE * y[e] - S * xa[e]);
        un2p += u[e] * u[e];
        xup  += xa[e] * u[e];
    }
#pragma unroll
    for (int m = 1; m < 32; m <<= 1) {
        un2p += __shfl_xor(un2p, m, 32);
        xup  += __shfl_xor(xup,  m, 32);
    }
    float un  = sqrtf(fmaxf(un2p, 1e-15f));
    float e2  = __expf(2.f * un * rcpf(bE));
    float th  = 1.f - 2.f * rcpf(e2 + 1.f);   // tanh(un/b)
    float s2  = th * rcpf(un);
    float xy  = s2 * xup;
    float y2s = th * th;
    float coef = 1.f + 2.f * xy + y2s;
    float den  = fmaxf(1.f + 2.f * xy + x2 * y2s, 1e-15f);
    float rd   = rcpf(den);
    float4v o = { (coef*xa[0] + bE*s2*u[0])*rd, (coef*xa[1] + bE*s2*u[1])*rd,
                  (coef*xa[2] + bE*s2*u[2])*rd, (coef*xa[3] + bE*s2*u[3])*rd };
    ((float4v*)out)[row * 32 + l32] = o;
}

extern "C" void kernel_launch(void* const* d_in, const int* in_sizes, int n_in,
                              void* d_out, int out_size, void* d_ws, size_t ws_size,
                              hipStream_t stream) {
    const float* x    = (const float*)d_in[0];
    const float* adj  = (const float*)d_in[1];
    const float* w    = (const float*)d_in[2];
    const float* batt = (const float*)d_in[3];
    float* out = (float*)d_out;

    float* Yp    = (float*)d_ws;            // 8 * 131072 floats
    float* Sp2   = Yp + 8 * 131072;         // 8 * 1024 * 64 floats (2 MB)
    float* st_x2 = Sp2 + 8 * 1024 * 64;     // 1024
    float* st_L  = st_x2 + 1024;            // 1024
    float* st_R  = st_L + 1024;             // 1024
    unsigned short* XbSw  = (unsigned short*)(st_R + 1024);   // 131072 shorts
    unsigned short* XbtSw = XbSw + 131072;                    // 131072 shorts

    hipLaunchKernelGGL(hyp_prep, dim3(16), dim3(256), 0, stream,
                       x, w, batt, XbSw, XbtSw, st_x2, st_L, st_R);
    hipLaunchKernelGGL(hyp_main, dim3(64, 8), dim3(256), 0, stream,
                       XbSw, XbtSw, adj, st_x2, st_L, st_R, Yp, Sp2);
    hipLaunchKernelGGL(hyp_exp, dim3(128), dim3(256), 0, stream,
                       x, Yp, Sp2, st_x2, out);
}

// Round 10
// 75.409 us; speedup vs baseline: 1.0490x; 1.0490x over previous
//
#include <hip/hip_runtime.h>
#include <math.h>

// HypAgg (Poincare ball, c=1), 3 dispatches — measured-best structure (r8).
//   g_ij = att_ij * atanh(sn_ij)/sn_ij / den_ij
//   support_i = beta_i * ( -S_i x_i + beta_i Y_i ),  S=sum g*alpha, Y=sum g x_j
// hyp_stats: per-row x2 / left / right (1024 rows, trivial).
// hyp_main : grid (64 i-tiles x 8 j-chunks of 128), 2 blocks/CU, TWO barriers.
//   Stats prefetched to regs; S partials straight to global (no in-block reduce).
// hyp_exp  : sums 8 Y partials + 64 S partials per row + expmap (256 blocks).
// ws floats: Yp[8*131072] | Sp2[8*1024*64] | st_x2[1024] | st_L[1024] | st_R[1024]
//
// Cross-round evidence (r2..r9): fixed harness cost 57.6us (40.7 poison fill at
// 83% HBM peak + ~17 replay/restore); exec plateau 14.7-15.7us across 8
// structurally different implementations — per-node replay + boundary flush +
// ~5us latency-bound kernels. This file is the best measured point (72.3).

typedef short short4v __attribute__((ext_vector_type(4)));
typedef short short8v __attribute__((ext_vector_type(8)));
typedef float float4v __attribute__((ext_vector_type(4)));

static __device__ __forceinline__ short f2bf(float f) {
    unsigned u = __float_as_uint(f);
    u += 0x7fff + ((u >> 16) & 1);   // RNE; inputs never NaN here
    return (short)(u >> 16);
}
static __device__ __forceinline__ float rcpf(float x) { return __builtin_amdgcn_rcpf(x); }
static __device__ __forceinline__ short8v ld8(const unsigned short* p) {
    short4v lo = *(const short4v*)p;        // LDS: two b64 reads (8B-aligned)
    short4v hi = *(const short4v*)(p + 4);
    return (short8v){lo[0],lo[1],lo[2],lo[3],hi[0],hi[1],hi[2],hi[3]};
}
static __device__ __forceinline__ float dot4(float4v a, float4v b) {
    return a[0]*b[0] + a[1]*b[1] + a[2]*b[2] + a[3]*b[3];
}
static __device__ __forceinline__ float atanh_over(float pn) {   // atanh(min(pn,1-eps))/pn
    float uu = fminf(pn, 1.f - 1e-7f);
    return 0.5f * __logf((1.f + uu) * rcpf(1.f - uu)) * rcpf(pn);
}

// ---------------- kernel 1: per-row stats ----------------
__global__ __launch_bounds__(256) void hyp_stats(
    const float* __restrict__ x, const float* __restrict__ w,
    const float* __restrict__ battp,
    float* __restrict__ st_x2, float* __restrict__ st_L, float* __restrict__ st_R)
{
    int row  = blockIdx.x * 4 + (threadIdx.x >> 6);
    int lane = threadIdx.x & 63;
    const float* xr = x + row * 128;
    float a0 = xr[lane], a1 = xr[lane + 64];
    float x2 = a0 * a0 + a1 * a1;
    float dl = a0 * w[lane]       + a1 * w[lane + 64];
    float dr = a0 * w[lane + 128] + a1 * w[lane + 192];
    for (int m = 1; m < 64; m <<= 1) {
        x2 += __shfl_xor(x2, m);
        dl += __shfl_xor(dl, m);
        dr += __shfl_xor(dr, m);
    }
    if (lane == 0) {
        float pn = sqrtf(fmaxf(x2, 1e-15f));
        float f  = atanh_over(pn);
        st_x2[row] = x2;
        st_L[row]  = f * dl + battp[0];   // DenseAtt left + bias folded
        st_R[row]  = f * dr;
    }
}

// ---------------- kernel 2: pairwise MFMA + scalar map (2 barriers) ----------------
__global__ __launch_bounds__(256, 2) void hyp_main(
    const float* __restrict__ x, const float* __restrict__ adj,
    const float* __restrict__ st_x2, const float* __restrict__ st_L,
    const float* __restrict__ st_R,
    float* __restrict__ Yp, float* __restrict__ Sp2)
{
    __shared__ unsigned short sXI [16 * 132];   // X_I  bf16 (i, dim)
    __shared__ unsigned short sXJ [128 * 132];  // X_J  bf16 (j, dim)
    __shared__ unsigned short sXJt[128 * 132];  // X_J^T bf16 (dim, j)
    __shared__ unsigned short sW  [16 * 132];   // g weights bf16 (i, j)

    const int t    = threadIdx.x;
    const int lane = t & 63;
    const int wave = t >> 6;
    const int n    = lane & 15;
    const int q    = lane >> 4;
    const int i0   = blockIdx.x * 16;
    const int c    = blockIdx.y;
    const int j0   = c * 128;

    const float4v* x4 = (const float4v*)x;

    // ---- register prefetch (independent; overlaps staging) ----
    float x2i4[4], bi4[4], li4[4];
#pragma unroll
    for (int r = 0; r < 4; ++r) {
        int i = i0 + q * 4 + r;
        x2i4[r] = st_x2[i];
        li4[r]  = st_L[i];
    }
    float x2j2[2], rj2[2], adjv[2][4];
#pragma unroll
    for (int jsl = 0; jsl < 2; ++jsl) {
        int j = j0 + (wave * 2 + jsl) * 16 + n;
        x2j2[jsl] = st_x2[j];
        rj2[jsl]  = st_R[j];
#pragma unroll
        for (int r = 0; r < 4; ++r)
            adjv[jsl][r] = adj[(i0 + q * 4 + r) * 1024 + j];
    }
#pragma unroll
    for (int r = 0; r < 4; ++r) bi4[r] = 1.f - x2i4[r];

    // ---- stage X_I (16x128) fp32->bf16 ----
#pragma unroll
    for (int it = 0; it < 2; ++it) {
        int idx = t + it * 256;
        int r = idx >> 5, cc = idx & 31;
        float4v v = x4[(i0 + r) * 32 + cc];
        short4v h = { f2bf(v[0]), f2bf(v[1]), f2bf(v[2]), f2bf(v[3]) };
        *(short4v*)&sXI[r * 132 + cc * 4] = h;
    }
    // ---- stage X_J row-major + transposed via 4x4 micro-blocks ----
    // bid bits: [0..3]=dcL, [4..5]=jrL, [6..8]=jrH, [9]=dcH
#pragma unroll
    for (int it = 0; it < 4; ++it) {
        int bid = t + it * 256;
        int jr = ((bid >> 4) & 3) | (((bid >> 6) & 7) << 2);   // 0..31
        int dc = (bid & 15) | (((bid >> 9) & 1) << 4);         // 0..31
        float4v v[4];
#pragma unroll
        for (int e = 0; e < 4; ++e)
            v[e] = x4[(j0 + jr * 4 + e) * 32 + dc];
        short4v h[4];
#pragma unroll
        for (int e = 0; e < 4; ++e) {
            h[e] = (short4v){ f2bf(v[e][0]), f2bf(v[e][1]), f2bf(v[e][2]), f2bf(v[e][3]) };
            *(short4v*)&sXJ[(jr * 4 + e) * 132 + dc * 4] = h[e];
        }
#pragma unroll
        for (int d = 0; d < 4; ++d) {
            short4v ht = (short4v){ h[0][d], h[1][d], h[2][d], h[3][d] };
            *(short4v*)&sXJt[(dc * 4 + d) * 132 + jr * 4] = ht;
        }
    }
    __syncthreads();   // B1: staging visible

    // ---- A-frags ----
    short8v afrag[4];
#pragma unroll
    for (int kk = 0; kk < 4; ++kk)
        afrag[kk] = ld8(&sXI[n * 132 + kk * 32 + q * 8]);

    float Sacc[4] = {0.f, 0.f, 0.f, 0.f};

    // ---- phase A: G = X_I * X_J^T + scalar map -> sW, Sacc ----
#pragma unroll
    for (int jsl = 0; jsl < 2; ++jsl) {
        int js = wave * 2 + jsl;
        int jrow = js * 16 + n;
        float4v acc = (float4v){0.f, 0.f, 0.f, 0.f};
#pragma unroll
        for (int kk = 0; kk < 4; ++kk) {
            short8v b = ld8(&sXJ[jrow * 132 + kk * 32 + q * 8]);
            acc = __builtin_amdgcn_mfma_f32_16x16x32_bf16(afrag[kk], b, acc, 0, 0, 0);
        }
        float x2j = x2j2[jsl];
        float rj  = rj2[jsl];
#pragma unroll
        for (int r = 0; r < 4; ++r) {
            float G     = acc[r];
            int   i     = q * 4 + r;
            float alpha = 1.f - 2.f * G + x2j;
            float den   = fmaxf(fmaf(x2i4[r], x2j, 1.f - 2.f * G), 1e-15f);
            float rdn   = rcpf(den);
            float bb    = bi4[r];
            float nn2   = alpha * alpha * x2i4[r] + bb * bb * x2j - 2.f * alpha * bb * G;
            float sn    = sqrtf(fmaxf(nn2 * rdn * rdn, 1e-15f));
            float tt    = atanh_over(sn);
            float z     = li4[r] + rj;
            float sig   = rcpf(1.f + __expf(-z));
            float g     = sig * adjv[jsl][r] * tt * rdn;
            Sacc[r]     = fmaf(g, alpha, Sacc[r]);
            sW[i * 132 + js * 16 + n] = (unsigned short)f2bf(g);
        }
    }
    __syncthreads();   // B2: sW ready

    // ---- phase B: Y = W(16x128) * X_J(128x128) via sXJt ----
    float4v accB[2];
    accB[0] = (float4v){0.f, 0.f, 0.f, 0.f};
    accB[1] = (float4v){0.f, 0.f, 0.f, 0.f};
#pragma unroll
    for (int nsl = 0; nsl < 2; ++nsl) {
        int ns = wave * 2 + nsl;
#pragma unroll
        for (int kk = 0; kk < 4; ++kk) {
            short8v a = ld8(&sW  [n * 132 + kk * 32 + q * 8]);
            short8v b = ld8(&sXJt[(ns * 16 + n) * 132 + kk * 32 + q * 8]);
            accB[nsl] = __builtin_amdgcn_mfma_f32_16x16x32_bf16(a, b, accB[nsl], 0, 0, 0);
        }
    }

    // ---- stores: Y partials + raw S partials (no reduction, no barrier) ----
    float* Yc = Yp + c * 131072;
#pragma unroll
    for (int nsl = 0; nsl < 2; ++nsl) {
        int ns = wave * 2 + nsl;
#pragma unroll
        for (int r = 0; r < 4; ++r)
            Yc[(i0 + q * 4 + r) * 128 + ns * 16 + n] = accB[nsl][r];
    }
    // Sp2[c][row][wave][n]: 64 partials per (chunk,row)
#pragma unroll
    for (int r = 0; r < 4; ++r)
        Sp2[((c * 1024 + i0 + q * 4 + r) * 4 + wave) * 16 + n] = Sacc[r];
}

// ---------------- kernel 3: sum partials + expmap ----------------
// 256 blocks x 256 threads: 4 rows/block (faster ramp), 32 lanes/row, 4 dims/lane.
__global__ __launch_bounds__(256) void hyp_exp(
    const float* __restrict__ x, const float* __restrict__ Yp,
    const float* __restrict__ Sp2, const float* __restrict__ st_x2,
    float* __restrict__ out)
{
    const int t   = threadIdx.x;
    const int row = blockIdx.x * 4 + (t >> 5);
    const int l32 = t & 31;
    float4v y = (float4v){0.f, 0.f, 0.f, 0.f};
    float S = 0.f;
#pragma unroll
    for (int c = 0; c < 8; ++c) {
        y += *(const float4v*)&Yp[c * 131072 + row * 128 + l32 * 4];
        S += Sp2[(c * 1024 + row) * 64 + l32];
        S += Sp2[(c * 1024 + row) * 64 + 32 + l32];
    }
#pragma unroll
    for (int m = 1; m < 32; m <<= 1) S += __shfl_xor(S, m, 32);

    float4v xa = ((const float4v*)x)[row * 32 + l32];
    float x2 = st_x2[row];
    float bE = fmaxf(1.f - x2, 1e-15f);
    float u[4], un2p = 0.f, xup = 0.f;
#pragma unroll
    for (int e = 0; e < 4; ++e) {
        u[e] = bE * (bE * y[e] - S * xa[e]);
        un2p += u[e] * u[e];
        xup  += xa[e] * u[e];
    }
#pragma unroll
    for (int m = 1; m < 32; m <<= 1) {
        un2p += __shfl_xor(un2p, m, 32);
        xup  += __shfl_xor(xup,  m, 32);
    }
    float un  = sqrtf(fmaxf(un2p, 1e-15f));
    float e2  = __expf(2.f * un * rcpf(bE));
    float th  = 1.f - 2.f * rcpf(e2 + 1.f);   // tanh(un/b)
    float s2  = th * rcpf(un);
    float xy  = s2 * xup;
    float y2s = th * th;
    float coef = 1.f + 2.f * xy + y2s;
    float den  = fmaxf(1.f + 2.f * xy + x2 * y2s, 1e-15f);
    float rd   = rcpf(den);
    float4v o = { (coef*xa[0] + bE*s2*u[0])*rd, (coef*xa[1] + bE*s2*u[1])*rd,
                  (coef*xa[2] + bE*s2*u[2])*rd, (coef*xa[3] + bE*s2*u[3])*rd };
    ((float4v*)out)[row * 32 + l32] = o;
}

extern "C" void kernel_launch(void* const* d_in, const int* in_sizes, int n_in,
                              void* d_out, int out_size, void* d_ws, size_t ws_size,
                              hipStream_t stream) {
    const float* x    = (const float*)d_in[0];
    const float* adj  = (const float*)d_in[1];
    const float* w    = (const float*)d_in[2];
    const float* batt = (const float*)d_in[3];
    float* out = (float*)d_out;

    float* Yp    = (float*)d_ws;            // 8 * 131072 floats
    float* Sp2   = Yp + 8 * 131072;         // 8 * 1024 * 64 floats (2 MB)
    float* st_x2 = Sp2 + 8 * 1024 * 64;     // 1024
    float* st_L  = st_x2 + 1024;            // 1024
    float* st_R  = st_L + 1024;             // 1024

    hipLaunchKernelGGL(hyp_stats, dim3(256), dim3(256), 0, stream,
                       x, w, batt, st_x2, st_L, st_R);
    hipLaunchKernelGGL(hyp_main, dim3(64, 8), dim3(256), 0, stream,
                       x, adj, st_x2, st_L, st_R, Yp, Sp2);
    hipLaunchKernelGGL(hyp_exp, dim3(256), dim3(256), 0, stream,
                       x, Yp, Sp2, st_x2, out);
}